// Round 1
// baseline (268.192 us; speedup 1.0000x reference)
//
#include <hip/hip_runtime.h>

// out[b,o] = sum_i x[b,i] * (mean[b,i,o] + W[b,i,o] * softplus(log_std[b,i,o])) + bias[o]
// Shapes: x[512,512], W/mean/log_std[512,512,512] f32, bias[512], out[512,512] f32.
// Memory-bound: 1.61 GB streamed per call -> roofline ~256 us @ 6.3 TB/s.

constexpr int BATCH = 512;
constexpr int D_IN  = 512;
constexpr int D_OUT = 512;

__device__ __forceinline__ float softplus_f(float v) {
    // log_std is in [-0.077, 0.077]; no overflow concerns. Hardware exp/log.
    return __logf(1.0f + __expf(v));
}

__global__ __launch_bounds__(512)
void bayes_matvec(const float* __restrict__ x,
                  const float* __restrict__ W,
                  const float* __restrict__ mean,
                  const float* __restrict__ log_std,
                  const float* __restrict__ bias,
                  float* __restrict__ out)
{
    const int b   = blockIdx.x;
    const int tid = threadIdx.x;
    const int o4  = tid & 127;   // which float4 of the 512-wide output row
    const int ig  = tid >> 7;    // i-stripe 0..3

    __shared__ float  s_x[D_IN];            // 2 KB
    __shared__ float4 s_red[3][128];        // 6 KB partials for stripes 1..3

    // Stage x[b,:] once (512 threads, 512 elements).
    s_x[tid] = x[(size_t)b * D_IN + tid];
    __syncthreads();

    const size_t tile = (size_t)b * D_IN * D_OUT + (size_t)o4 * 4;
    const float4* __restrict__ pW = reinterpret_cast<const float4*>(W      + tile);
    const float4* __restrict__ pM = reinterpret_cast<const float4*>(mean    + tile);
    const float4* __restrict__ pS = reinterpret_cast<const float4*>(log_std + tile);
    constexpr int ROW4 = D_OUT / 4;  // float4 row stride

    float4 acc = make_float4(0.f, 0.f, 0.f, 0.f);

    #pragma unroll 4
    for (int i = ig; i < D_IN; i += 4) {
        const int ro = i * ROW4;
        float4 w = pW[ro];
        float4 m = pM[ro];
        float4 s = pS[ro];
        float xv = s_x[i];
        acc.x = fmaf(xv, fmaf(w.x, softplus_f(s.x), m.x), acc.x);
        acc.y = fmaf(xv, fmaf(w.y, softplus_f(s.y), m.y), acc.y);
        acc.z = fmaf(xv, fmaf(w.z, softplus_f(s.z), m.z), acc.z);
        acc.w = fmaf(xv, fmaf(w.w, softplus_f(s.w), m.w), acc.w);
    }

    if (ig > 0) {
        s_red[ig - 1][o4] = acc;
    }
    __syncthreads();

    if (ig == 0) {
        float4 r1 = s_red[0][o4];
        float4 r2 = s_red[1][o4];
        float4 r3 = s_red[2][o4];
        float4 bz = reinterpret_cast<const float4*>(bias)[o4];
        float4 r;
        r.x = acc.x + r1.x + r2.x + r3.x + bz.x;
        r.y = acc.y + r1.y + r2.y + r3.y + bz.y;
        r.z = acc.z + r1.z + r2.z + r3.z + bz.z;
        r.w = acc.w + r1.w + r2.w + r3.w + bz.w;
        reinterpret_cast<float4*>(out + (size_t)b * D_OUT)[o4] = r;
    }
}

extern "C" void kernel_launch(void* const* d_in, const int* in_sizes, int n_in,
                              void* d_out, int out_size, void* d_ws, size_t ws_size,
                              hipStream_t stream) {
    const float* x       = (const float*)d_in[0];
    const float* W       = (const float*)d_in[1];
    const float* mean    = (const float*)d_in[2];
    const float* log_std = (const float*)d_in[3];
    const float* bias    = (const float*)d_in[4];
    float* out = (float*)d_out;

    bayes_matvec<<<BATCH, 512, 0, stream>>>(x, W, mean, log_std, bias, out);
}